// Round 1
// baseline (65.536 us; speedup 1.0000x reference)
//
#include <hip/hip_runtime.h>
#include <math.h>

#define SEQ 4096
#define TPB 256
#define CHUNK (SEQ / TPB)  // 16

__global__ __launch_bounds__(TPB) void probs_to_span_kernel(
    const float* __restrict__ start_p,
    const float* __restrict__ end_p,
    float* __restrict__ out, int B) {
  const int b = blockIdx.x;
  const int t = threadIdx.x;
  const float* sp = start_p + (size_t)b * SEQ;
  const float* ep = end_p + (size_t)b * SEQ;

  // Load this thread's contiguous 16-element chunk of start/end as float4.
  float s_vals[CHUNK], e_vals[CHUNK];
  const float4* sp4 = (const float4*)(sp + t * CHUNK);
  const float4* ep4 = (const float4*)(ep + t * CHUNK);
#pragma unroll
  for (int k = 0; k < CHUNK / 4; ++k) {
    float4 sv = sp4[k];
    float4 ev = ep4[k];
    s_vals[4 * k + 0] = sv.x; s_vals[4 * k + 1] = sv.y;
    s_vals[4 * k + 2] = sv.z; s_vals[4 * k + 3] = sv.w;
    e_vals[4 * k + 0] = ev.x; e_vals[4 * k + 1] = ev.y;
    e_vals[4 * k + 2] = ev.z; e_vals[4 * k + 3] = ev.w;
  }

  // Per-chunk maxima.
  float cmax_s = s_vals[0], cmax_e = e_vals[0];
#pragma unroll
  for (int k = 1; k < CHUNK; ++k) {
    cmax_s = fmaxf(cmax_s, s_vals[k]);
    cmax_e = fmaxf(cmax_e, e_vals[k]);
  }

  __shared__ float sh_cs[TPB], sh_ce[TPB];
  __shared__ float sh_pref[TPB];  // exclusive prefix max of chunk start-maxima
  __shared__ float sh_suff[TPB];  // exclusive suffix max of chunk end-maxima
  sh_cs[t] = cmax_s;
  sh_ce[t] = cmax_e;
  __syncthreads();

  // Serial exclusive scans over 256 chunk maxima (cheap; 2 threads in parallel).
  if (t == 0) {
    float run = -INFINITY;
    for (int i = 0; i < TPB; ++i) { sh_pref[i] = run; run = fmaxf(run, sh_cs[i]); }
  } else if (t == 1) {
    float run = -INFINITY;
    for (int i = TPB - 1; i >= 0; --i) { sh_suff[i] = run; run = fmaxf(run, sh_ce[i]); }
  }
  __syncthreads();

  // --- predicted_start: row_max[s] = start[s] * suffmax_end[s] (t >= s) ---
  float suffm[CHUNK];
  float run = sh_suff[t];
#pragma unroll
  for (int k = CHUNK - 1; k >= 0; --k) {
    run = fmaxf(run, e_vals[k]);
    suffm[k] = run;
  }
  float bestv = -INFINITY;
  int besti = 0;
#pragma unroll
  for (int k = 0; k < CHUNK; ++k) {
    float v = s_vals[k] * suffm[k];
    if (v > bestv) { bestv = v; besti = t * CHUNK + k; }  // strict > keeps first occurrence
  }

  // --- predicted_end: col_max[t] = end[t] * prefmax_start[t] (s <= t) ---
  run = sh_pref[t];
  float bestv2 = -INFINITY;
  int besti2 = 0;
#pragma unroll
  for (int k = 0; k < CHUNK; ++k) {
    run = fmaxf(run, s_vals[k]);
    float v = e_vals[k] * run;
    if (v > bestv2) { bestv2 = v; besti2 = t * CHUNK + k; }
  }

  // Block argmax reduction; on equal values prefer lower index (first occurrence).
  __shared__ float rv[TPB];  __shared__ int ri[TPB];
  __shared__ float rv2[TPB]; __shared__ int ri2[TPB];
  rv[t] = bestv;  ri[t] = besti;
  rv2[t] = bestv2; ri2[t] = besti2;
  __syncthreads();
  for (int off = TPB / 2; off > 0; off >>= 1) {
    if (t < off) {
      // thread t's current champion covers lower indices than t+off's:
      // only replace on strictly greater value.
      if (rv[t + off] > rv[t])  { rv[t] = rv[t + off];  ri[t] = ri[t + off]; }
      if (rv2[t + off] > rv2[t]) { rv2[t] = rv2[t + off]; ri2[t] = ri2[t + off]; }
    }
    __syncthreads();
  }

  if (t == 0) {
    out[b] = (float)ri[0];        // predicted_start
    out[B + b] = (float)ri2[0];   // predicted_end
  }
}

extern "C" void kernel_launch(void* const* d_in, const int* in_sizes, int n_in,
                              void* d_out, int out_size, void* d_ws, size_t ws_size,
                              hipStream_t stream) {
  const float* start_p = (const float*)d_in[0];
  const float* end_p = (const float*)d_in[1];
  float* out = (float*)d_out;
  const int B = in_sizes[0] / SEQ;  // 16
  probs_to_span_kernel<<<B, TPB, 0, stream>>>(start_p, end_p, out, B);
}

// Round 3
// 55.691 us; speedup vs baseline: 1.1768x; 1.1768x over previous
//
#include <hip/hip_runtime.h>
#include <math.h>

#define SEQ 4096
#define TPB 256
#define CHUNK (SEQ / TPB)  // 16
#define NWAVE (TPB / 64)   // 4

__global__ __launch_bounds__(TPB) void probs_to_span_kernel(
    const float* __restrict__ start_p,
    const float* __restrict__ end_p,
    float* __restrict__ out, int B) {
  const int b = blockIdx.x;
  const int t = threadIdx.x;
  const int lane = t & 63;
  const int wave = t >> 6;

  const float4* sp4 = (const float4*)(start_p + (size_t)b * SEQ + t * CHUNK);
  const float4* ep4 = (const float4*)(end_p + (size_t)b * SEQ + t * CHUNK);

  float s_vals[CHUNK], e_vals[CHUNK];
#pragma unroll
  for (int k = 0; k < CHUNK / 4; ++k) {
    float4 sv = sp4[k];
    float4 ev = ep4[k];
    s_vals[4 * k + 0] = sv.x; s_vals[4 * k + 1] = sv.y;
    s_vals[4 * k + 2] = sv.z; s_vals[4 * k + 3] = sv.w;
    e_vals[4 * k + 0] = ev.x; e_vals[4 * k + 1] = ev.y;
    e_vals[4 * k + 2] = ev.z; e_vals[4 * k + 3] = ev.w;
  }

  // Per-chunk maxima.
  float cmax_s = s_vals[0], cmax_e = e_vals[0];
#pragma unroll
  for (int k = 1; k < CHUNK; ++k) {
    cmax_s = fmaxf(cmax_s, s_vals[k]);
    cmax_e = fmaxf(cmax_e, e_vals[k]);
  }

  // ---- Wave-parallel scans over the 256 chunk maxima ----
  // Inclusive prefix-max scan of cmax_s within the wave (shfl_up).
  float xs = cmax_s;
#pragma unroll
  for (int off = 1; off < 64; off <<= 1) {
    float v = __shfl_up(xs, off, 64);
    if (lane >= off) xs = fmaxf(xs, v);
  }
  float ex_pref = (lane == 0) ? -INFINITY : __shfl_up(xs, 1, 64);  // exclusive, intra-wave
  float wave_tot_s = __shfl(xs, 63, 64);                           // wave's full max

  // Inclusive suffix-max scan of cmax_e within the wave (shfl_down).
  float xe = cmax_e;
#pragma unroll
  for (int off = 1; off < 64; off <<= 1) {
    float v = __shfl_down(xe, off, 64);
    if (lane < 64 - off) xe = fmaxf(xe, v);
  }
  float ex_suff = (lane == 63) ? -INFINITY : __shfl_down(xe, 1, 64);
  float wave_tot_e = __shfl(xe, 0, 64);

  // Combine across the 4 waves via LDS.
  __shared__ float sh_tot_s[NWAVE], sh_tot_e[NWAVE];
  if (lane == 0) { sh_tot_s[wave] = wave_tot_s; sh_tot_e[wave] = wave_tot_e; }
  __syncthreads();
  float wpref = -INFINITY, wsuff = -INFINITY;
#pragma unroll
  for (int w = 0; w < NWAVE; ++w) {
    if (w < wave) wpref = fmaxf(wpref, sh_tot_s[w]);
    if (w > wave) wsuff = fmaxf(wsuff, sh_tot_e[w]);
  }
  float pref = fmaxf(wpref, ex_pref);  // exclusive prefix-max of start chunk-maxima
  float suff = fmaxf(wsuff, ex_suff);  // exclusive suffix-max of end chunk-maxima

  // ---- predicted_start: row_max[s] = start[s] * suffmax_end[s] (t >= s) ----
  float suffm[CHUNK];
  float run = suff;
#pragma unroll
  for (int k = CHUNK - 1; k >= 0; --k) {
    run = fmaxf(run, e_vals[k]);
    suffm[k] = run;
  }
  float bestv = -INFINITY; int besti = 0;
#pragma unroll
  for (int k = 0; k < CHUNK; ++k) {
    float v = s_vals[k] * suffm[k];
    if (v > bestv) { bestv = v; besti = t * CHUNK + k; }  // strict > = first occurrence
  }

  // ---- predicted_end: col_max[t] = end[t] * prefmax_start[t] (s <= t) ----
  run = pref;
  float bestv2 = -INFINITY; int besti2 = 0;
#pragma unroll
  for (int k = 0; k < CHUNK; ++k) {
    run = fmaxf(run, s_vals[k]);
    float v = e_vals[k] * run;
    if (v > bestv2) { bestv2 = v; besti2 = t * CHUNK + k; }
  }

  // ---- In-wave argmax reductions (lane i's span is lower-indexed than lane i+off's,
  //      so strict > keeps the first occurrence). ----
#pragma unroll
  for (int off = 32; off > 0; off >>= 1) {
    float ov = __shfl_down(bestv, off, 64);
    int   oi = __shfl_down(besti, off, 64);
    if (ov > bestv) { bestv = ov; besti = oi; }
    float ov2 = __shfl_down(bestv2, off, 64);
    int   oi2 = __shfl_down(besti2, off, 64);
    if (ov2 > bestv2) { bestv2 = ov2; besti2 = oi2; }
  }

  // Combine the 4 wave champions (ascending wave order = ascending index ranges).
  __shared__ float sh_v[NWAVE], sh_v2[NWAVE];
  __shared__ int   sh_i[NWAVE], sh_i2[NWAVE];
  if (lane == 0) { sh_v[wave] = bestv; sh_i[wave] = besti;
                   sh_v2[wave] = bestv2; sh_i2[wave] = besti2; }
  __syncthreads();
  if (t == 0) {
    float fv = sh_v[0];  int fi = sh_i[0];
    float fv2 = sh_v2[0]; int fi2 = sh_i2[0];
#pragma unroll
    for (int w = 1; w < NWAVE; ++w) {
      if (sh_v[w] > fv)   { fv = sh_v[w];   fi = sh_i[w]; }
      if (sh_v2[w] > fv2) { fv2 = sh_v2[w]; fi2 = sh_i2[w]; }
    }
    out[b] = (float)fi;       // predicted_start
    out[B + b] = (float)fi2;  // predicted_end
  }
}

extern "C" void kernel_launch(void* const* d_in, const int* in_sizes, int n_in,
                              void* d_out, int out_size, void* d_ws, size_t ws_size,
                              hipStream_t stream) {
  const float* start_p = (const float*)d_in[0];
  const float* end_p = (const float*)d_in[1];
  float* out = (float*)d_out;
  const int B = in_sizes[0] / SEQ;  // 16
  probs_to_span_kernel<<<B, TPB, 0, stream>>>(start_p, end_p, out, B);
}